// Round 11
// baseline (119.445 us; speedup 1.0000x reference)
//
#include <hip/hip_runtime.h>

#define B 8
#define N 8192
#define M 2048
#define NITER 4
#define BASE_ALPHA 0.1f

#define NTHR 1024              // 16 waves (4 waves/SIMD, 1 block/CU)
#define NPT 32                 // point-lanes per split
#define NSPLIT 32              // j-splits per block
#define JS 64                  // y's per split
#define JQ 16                  // j-quads per split
#define PT 8                   // points per thread
#define PPB 256                // points per block
#define NBLK 256               // 256 blocks
#define BPB 32                 // blocks per batch
#define NSLOT (BPB * 4)        // 128 per-owner-wave slots per batch

// Kernel boundaries are the cross-block barrier (R6-R8: in-kernel cross-block sync
// cost ~200us in every variant). ws:
//   pos4  float4[B*N] @0        {x,y,z,|r|^2}
//   aux4  float4[B*N] @1MB      {md, ynear0, ynear1, ynear2}  (no tile needed to apply)
//   slots float[2][B][NSLOT] @2MB  parity double-buffered (fixes same-kernel WAR race)
#define OFF_AUX   (1024 * 1024)
#define OFF_SLOTS (2 * 1024 * 1024)

// LDS tile SoA-by-4, physical quad index jq*32+sp: pass-1 reads are half-wave uniform
// (2 distinct addrs/wave = free); pass-2 touches ONE quad per owner (argmin-quad is
// tracked in pass-1), killing R10's ~8-way-conflict full-split re-scan.

typedef float f2 __attribute__((ext_vector_type(2)));

__device__ __forceinline__ unsigned int ord32(float t) {
    unsigned int u = __float_as_uint(t);
    return u ^ ((unsigned int)((int)u >> 31) | 0x80000000u);   // float order -> uint order
}
__device__ __forceinline__ float dec32(unsigned int h) {
    return __uint_as_float((h & 0x80000000u) ? (h ^ 0x80000000u) : ~h);
}

__global__ __launch_bounds__(NTHR, 4) void iter_kernel(const float* __restrict__ pred,
                                                       const float* __restrict__ partial,
                                                       float4* __restrict__ pos4,
                                                       float4* __restrict__ aux4,
                                                       const float* __restrict__ slots_in,
                                                       float* __restrict__ slots_out,
                                                       int iter) {
    __shared__ float4 sX[M / 4], sY[M / 4], sZ[M / 4], sW[M / 4];  // 32 KB
    __shared__ unsigned long long lkeys[16][PPB];                  // 32 KB
    __shared__ float4 lpos[PPB];                                   // 4 KB

    const int tid = threadIdx.x;
    const int b = blockIdx.x >> 5;
    const int blk = blockIdx.x & 31;
    const int gp0 = b * N + blk * PPB;
    const int wave = tid >> 6;

    // ---- phase 0 (parallel): waves 8-15 build tile; waves 0-3 apply prev update ----
    const float* pa = partial + b * M * 3;
    if (tid >= 512) {
        int u = tid - 512;                      // quad u: sp = u&31, jq = u>>5
        int sp = u & 31, jq = u >> 5;
        const float4* src = (const float4*)(pa + (sp * JS + jq * 4) * 3);  // 48B-mult offset
        float4 A = src[0], Bv = src[1], C = src[2];
        // A={a0,a1,a2,b0} Bv={b1,b2,c0,c1} C={c2,d0,d1,d2}  (-2y)*x bit-equal (-2x)*y
        sX[u] = make_float4(-2.f * A.x, -2.f * A.w, -2.f * Bv.z, -2.f * C.y);
        sY[u] = make_float4(-2.f * A.y, -2.f * Bv.x, -2.f * Bv.w, -2.f * C.z);
        sZ[u] = make_float4(-2.f * A.z, -2.f * Bv.y, -2.f * C.x, -2.f * C.w);
        sW[u] = make_float4(A.x * A.x + A.y * A.y + A.z * A.z,
                            A.w * A.w + Bv.x * Bv.x + Bv.y * Bv.y,
                            Bv.z * Bv.z + Bv.w * Bv.w + C.x * C.x,
                            C.y * C.y + C.z * C.z + C.w * C.w);
    } else if (tid < PPB) {
        const int p = gp0 + tid;
        float rx, ry, rz;
        if (iter == 0) {
            const float* pp = pred + (unsigned long long)p * 3;
            rx = pp[0]; ry = pp[1]; rz = pp[2];
        } else {
            float4 f = pos4[p];
            float4 a = aux4[p];                 // {md, y0, y1, y2}
            int lane = tid & 63;
            float2 sv = ((const float2*)(slots_in + b * NSLOT))[lane];  // 128 slots in-wave
            float wm = fmaxf(sv.x, sv.y);
            #pragma unroll
            for (int o = 32; o > 0; o >>= 1) wm = fmaxf(wm, __shfl_xor(wm, o));
            float inv = 1.0f / (wm + 1e-6f);
            float alpha = BASE_ALPHA * (2.0f - a.x * inv);
            rx = fmaf(alpha, a.y - f.x, f.x);
            ry = fmaf(alpha, a.z - f.y, f.y);
            rz = fmaf(alpha, a.w - f.z, f.z);
        }
        float w = rx * rx + ry * ry + rz * rz;
        lpos[tid] = make_float4(rx, ry, rz, w);
        pos4[p] = make_float4(rx, ry, rz, w);
    }
    __syncthreads();                            // sync 1: tile + lpos ready

    const int split = tid >> 5;                 // 0..31 (uniform per half-wave)
    const int pt = tid & 31;

    // ---- pass 1: packed min + argmin-QUAD tracking (2.75 VALU-instr/pair) ----
    f2 sx[PT], sy[PT], sz[PT];
    #pragma unroll
    for (int k = 0; k < PT; ++k) {
        float4 r = lpos[pt + k * NPT];
        sx[k] = (f2){r.x, r.x}; sy[k] = (f2){r.y, r.y}; sz[k] = (f2){r.z, r.z};
    }
    float acc[PT]; int idq[PT];
    #pragma unroll
    for (int k = 0; k < PT; ++k) { acc[k] = 3.402823466e+38f; idq[k] = 0; }

    #pragma unroll 4
    for (int jq = 0; jq < JQ; ++jq) {
        float4 qx = sX[jq * 32 + split], qy = sY[jq * 32 + split];
        float4 qz = sZ[jq * 32 + split], qw = sW[jq * 32 + split];
        f2 qx01 = (f2){qx.x, qx.y}, qx23 = (f2){qx.z, qx.w};
        f2 qy01 = (f2){qy.x, qy.y}, qy23 = (f2){qy.z, qy.w};
        f2 qz01 = (f2){qz.x, qz.y}, qz23 = (f2){qz.z, qz.w};
        f2 qw01 = (f2){qw.x, qw.y}, qw23 = (f2){qw.z, qw.w};
        #pragma unroll
        for (int k = 0; k < PT; ++k) {
            f2 t01 = __builtin_elementwise_fma(sx[k], qx01,
                     __builtin_elementwise_fma(sy[k], qy01,
                     __builtin_elementwise_fma(sz[k], qz01, qw01)));
            f2 t23 = __builtin_elementwise_fma(sx[k], qx23,
                     __builtin_elementwise_fma(sy[k], qy23,
                     __builtin_elementwise_fma(sz[k], qz23, qw23)));
            f2 m2 = __builtin_elementwise_min(t01, t23);
            float h = fminf(m2.x, m2.y);        // exact quad min
            bool lt = h < acc[k];               // strict <: earliest jq kept on ties
            acc[k] = lt ? h : acc[k];
            idq[k] = lt ? jq : idq[k];
        }
    }

    // ---- merge (value, split*16+jq) across the wave's two splits ----
    #pragma unroll
    for (int k = 0; k < PT; ++k) {
        unsigned int hi = ord32(acc[k]);
        unsigned int lo = (unsigned int)(split * JQ + idq[k]);   // split-major: lex = first-idx
        unsigned int ohi = __shfl_xor(hi, 32), olo = __shfl_xor(lo, 32);
        if (ohi < hi || (ohi == hi && olo < lo)) { hi = ohi; lo = olo; }
        if ((tid & 32) == 0)
            lkeys[wave][pt + k * NPT] = (((unsigned long long)hi) << 32) | lo;
    }
    __syncthreads();                            // sync 2: lkeys ready

    // ---- owners: reduce 16 rows, re-scan ONE quad, write aux4 + per-wave slot ----
    if (tid < PPB) {
        unsigned long long best = lkeys[0][tid];
        #pragma unroll
        for (int r = 1; r < 16; ++r) {
            unsigned long long c = lkeys[r][tid];
            if (c < best) best = c;
        }
        const unsigned int code = (unsigned int)(best & 0xFFFFFFFFull);
        const int bsplit = (int)(code >> 4), bjq = (int)(code & 15);
        const float tstar = dec32((unsigned int)(best >> 32));
        const float4 f4 = lpos[tid];
        const float md = sqrtf(fmaxf(f4.w + tstar, 0.0f));

        // winning quad only: bit-identical scalar chains; earliest j wins ties
        const int qi = bjq * 32 + bsplit;
        float4 qx = sX[qi], qy = sY[qi], qz = sZ[qi], qw = sW[qi];
        float t0 = fmaf(f4.x, qx.x, fmaf(f4.y, qy.x, fmaf(f4.z, qz.x, qw.x)));
        float t1 = fmaf(f4.x, qx.y, fmaf(f4.y, qy.y, fmaf(f4.z, qz.y, qw.y)));
        float t2 = fmaf(f4.x, qx.z, fmaf(f4.y, qy.z, fmaf(f4.z, qz.z, qw.z)));
        float t3 = fmaf(f4.x, qx.w, fmaf(f4.y, qy.w, fmaf(f4.z, qz.w, qw.w)));
        float bt = t0, y0 = qx.x, y1 = qy.x, y2 = qz.x;
        if (t1 < bt) { bt = t1; y0 = qx.y; y1 = qy.y; y2 = qz.y; }
        if (t2 < bt) { bt = t2; y0 = qx.z; y1 = qy.z; y2 = qz.z; }
        if (t3 < bt) { bt = t3; y0 = qx.w; y1 = qy.w; y2 = qz.w; }
        aux4[gp0 + tid] = make_float4(md, -0.5f * y0, -0.5f * y1, -0.5f * y2);  // exact y

        float wm = md;
        #pragma unroll
        for (int o = 32; o > 0; o >>= 1) wm = fmaxf(wm, __shfl_down(wm, o));
        if ((tid & 63) == 0)
            slots_out[b * NSLOT + blk * 4 + wave] = wm;   // per-wave slot: no extra sync
    }
}

__global__ __launch_bounds__(256) void final_kernel(const float4* __restrict__ pos4,
                                                    const float4* __restrict__ aux4,
                                                    const float* __restrict__ slots_in,
                                                    float* __restrict__ out) {
    const int p = blockIdx.x * 256 + threadIdx.x;   // batch uniform per block
    const int b = p >> 13;
    int lane = threadIdx.x & 63;
    float2 sv = ((const float2*)(slots_in + b * NSLOT))[lane];
    float wm = fmaxf(sv.x, sv.y);
    #pragma unroll
    for (int o = 32; o > 0; o >>= 1) wm = fmaxf(wm, __shfl_xor(wm, o));
    float4 f = pos4[p];
    float4 a = aux4[p];
    float inv = 1.0f / (wm + 1e-6f);
    float alpha = BASE_ALPHA * (2.0f - a.x * inv);
    float* po = out + (unsigned long long)p * 3;
    po[0] = fmaf(alpha, a.y - f.x, f.x);
    po[1] = fmaf(alpha, a.z - f.y, f.y);
    po[2] = fmaf(alpha, a.w - f.z, f.z);
}

extern "C" void kernel_launch(void* const* d_in, const int* in_sizes, int n_in,
                              void* d_out, int out_size, void* d_ws, size_t ws_size,
                              hipStream_t stream) {
    const float* pred = (const float*)d_in[0];
    const float* partial = (const float*)d_in[1];
    char* ws = (char*)d_ws;
    float4* pos4 = (float4*)ws;
    float4* aux4 = (float4*)(ws + OFF_AUX);
    float* slots0 = (float*)(ws + OFF_SLOTS);          // parity 0
    float* slots1 = slots0 + B * NSLOT;                // parity 1
    float* out = (float*)d_out;

    for (int it = 0; it < NITER; ++it) {
        float* sin  = (it & 1) ? slots0 : slots1;      // read prev parity (unused at it=0)
        float* sout = (it & 1) ? slots1 : slots0;      // write own parity
        hipLaunchKernelGGL(iter_kernel, dim3(NBLK), dim3(NTHR), 0, stream,
                           pred, partial, pos4, aux4, sin, sout, it);
    }
    hipLaunchKernelGGL(final_kernel, dim3(B * N / 256), dim3(256), 0, stream,
                       pos4, aux4, ((NITER - 1) & 1) ? slots1 : slots0, out);
}